// Round 1
// 427.220 us; speedup vs baseline: 1.0983x; 1.0983x over previous
//
#include <hip/hip_runtime.h>
#include <math.h>

#define N_NODES 100000
#define HDIM    128
#define ODIM    40
#define NBLK    ((N_NODES + 255) / 256)   // 391

typedef unsigned short u16;
typedef unsigned int   u32;
typedef short bf16x8 __attribute__((ext_vector_type(8)));   // 8 bf16 in 4 VGPRs
typedef float f32x4  __attribute__((ext_vector_type(4)));

// ---------------- bf16 helpers ----------------
__device__ inline float bf16lo_to_f(u32 v) {
    u32 u = v << 16; float f; __builtin_memcpy(&f, &u, 4); return f;
}
__device__ inline float bf16hi_to_f(u32 v) {
    u32 u = v & 0xffff0000u; float f; __builtin_memcpy(&f, &u, 4); return f;
}
__device__ inline u16 f_to_bf16(float f) {
    u32 u; __builtin_memcpy(&u, &f, 4);
    u32 r = (u + 0x7fffu + ((u >> 16) & 1u)) >> 16;   // round-nearest-even
    return (u16)r;
}
__device__ inline u32 pack_bf16x2(float a, float b) {
    return (u32)f_to_bf16(a) | ((u32)f_to_bf16(b) << 16);
}

// ---------------------------------------------------------------------------
// CSR build (counting sort by dst).
// ---------------------------------------------------------------------------
__global__ __launch_bounds__(256) void count_deg_kernel(
    const int* __restrict__ dst, int* __restrict__ ic, int E)
{
    int e = blockIdx.x * 256 + threadIdx.x;
    if (e < E) atomicAdd(ic + dst[e], 1);
}

__global__ __launch_bounds__(256) void block_sum_kernel(
    const int* __restrict__ ic, int* __restrict__ bs, int n)
{
    __shared__ int sm[256];
    int t = threadIdx.x;
    int i = blockIdx.x * 256 + t;
    sm[t] = (i < n) ? ic[i] : 0;
    __syncthreads();
    for (int s = 128; s > 0; s >>= 1) {
        if (t < s) sm[t] += sm[t + s];
        __syncthreads();
    }
    if (t == 0) bs[blockIdx.x] = sm[0];
}

__global__ __launch_bounds__(512) void scan_bs_kernel(int* __restrict__ bs, int nb)
{
    __shared__ int sm[512];
    int t = threadIdx.x;
    sm[t] = (t < nb) ? bs[t] : 0;
    __syncthreads();
    for (int off = 1; off < 512; off <<= 1) {
        int v = (t >= off) ? sm[t - off] : 0;
        __syncthreads();
        sm[t] += v;
        __syncthreads();
    }
    if (t < nb) bs[t] = (t == 0) ? 0 : sm[t - 1];
}

__global__ __launch_bounds__(256) void scan_block_kernel(
    const int* __restrict__ ic, const int* __restrict__ bs,
    int* __restrict__ pc, int n)
{
    __shared__ int sm[256];
    int t = threadIdx.x;
    int i = blockIdx.x * 256 + t;
    int v = (i < n) ? ic[i] : 0;
    sm[t] = v;
    __syncthreads();
    for (int off = 1; off < 256; off <<= 1) {
        int u = (t >= off) ? sm[t - off] : 0;
        __syncthreads();
        sm[t] += u;
        __syncthreads();
    }
    if (i < n) pc[i] = bs[blockIdx.x] + sm[t] - v;   // exclusive
}

__global__ __launch_bounds__(256) void fill_kernel(
    const int* __restrict__ src, const int* __restrict__ dst,
    int* __restrict__ pc, int* __restrict__ cs, int E)
{
    int e = blockIdx.x * 256 + threadIdx.x;
    if (e < E) {
        int p = atomicAdd(pc + dst[e], 1);
        cs[p] = src[e];
    }
}
// after fill: end(n) = pc[n], start(n) = pc[n] - ic[n]

// ---------------------------------------------------------------------------
// fp32 -> bf16 feature conversion (2 elements / thread).
// ---------------------------------------------------------------------------
__global__ __launch_bounds__(256) void f2bf_kernel(
    const float2* __restrict__ in, u32* __restrict__ out, int n2)
{
    int i = blockIdx.x * 256 + threadIdx.x;
    if (i < n2) { float2 v = in[i]; out[i] = pack_bf16x2(v.x, v.y); }
}

// ---------------------------------------------------------------------------
// Pack 128x128 fp32 weight matrices into bf16 MFMA B-fragment order:
//   frag (ntile, kslice): 64 lanes x 8 bf16, lane = q*16 + (n&15),
//   element j: B[k = kslice*32 + q*8 + j][n = ntile*16 + (n&15)]
// ---------------------------------------------------------------------------
struct WPtrs { const float* w[7]; };

__global__ __launch_bounds__(256) void pack_w_kernel(WPtrs p, u16* __restrict__ out)
{
    int mat = blockIdx.y;
    int e = blockIdx.x * 256 + threadIdx.x;      // 0..16383
    int k = e >> 7, n = e & 127;
    float v = p.w[mat][e];
    int nt = n >> 4, ks = k >> 5, q = (k >> 3) & 3, j = k & 7;
    int dst = mat * 16384 + (((nt * 4 + ks) * 64 + q * 16 + (n & 15)) << 3) + j;
    out[dst] = f_to_bf16(v);
}

// Pack Wf2 [128][40] into 128x48 (zero-padded) B-frag order: 3 ntiles x 4 ks.
__global__ __launch_bounds__(256) void pack_wf2_kernel(
    const float* __restrict__ Wf2, u16* __restrict__ outp)
{
    int e = blockIdx.x * 256 + threadIdx.x;      // 0..6143 (128*48)
    if (e >= 128 * 48) return;
    int k = e / 48, n = e - k * 48;
    float v = (n < ODIM) ? Wf2[k * ODIM + n] : 0.f;
    int nt = n >> 4, ks = k >> 5, q = (k >> 3) & 3, j = k & 7;
    outp[(((nt * 4 + ks) * 64 + q * 16 + (n & 15)) << 3) + j] = f_to_bf16(v);
}

// ---------------------------------------------------------------------------
// Mean-gather on bf16 features, one wave per node, 4-way neighbor ILP.
// ---------------------------------------------------------------------------
__global__ __launch_bounds__(256) void gather_mean16_kernel(
    const u32* __restrict__ feat,    // [N][64] u32 (=128 bf16)
    const int* __restrict__ cs, const int* __restrict__ pc, const int* __restrict__ ic,
    u32* __restrict__ A)             // [N][64] u32
{
    const int wave = threadIdx.x >> 6;
    const int lane = threadIdx.x & 63;
    const int node = blockIdx.x * 4 + wave;
    const int end  = pc[node];
    const int deg  = ic[node];
    const int start = end - deg;
    const int g    = lane >> 4;       // neighbor sub-slot 0..3
    const int ch   = lane & 15;       // 16B chunk 0..15 within the row

    float acc[8] = {0.f,0.f,0.f,0.f,0.f,0.f,0.f,0.f};

    for (int b = start; b < end; b += 64) {
        int m = end - b; if (m > 64) m = 64;
        int idxv = cs[b + (lane < m ? lane : 0)];
        for (int j = 0; j < m; j += 4) {
            int nb = j + g;
            int s  = __shfl(idxv, nb, 64);
            uint4 v = {0u, 0u, 0u, 0u};
            if (nb < m)
                v = *reinterpret_cast<const uint4*>(feat + ((size_t)s << 6) + (ch << 2));
            acc[0] += bf16lo_to_f(v.x); acc[1] += bf16hi_to_f(v.x);
            acc[2] += bf16lo_to_f(v.y); acc[3] += bf16hi_to_f(v.y);
            acc[4] += bf16lo_to_f(v.z); acc[5] += bf16hi_to_f(v.z);
            acc[6] += bf16lo_to_f(v.w); acc[7] += bf16hi_to_f(v.w);
        }
    }

    #pragma unroll
    for (int off = 16; off < 64; off <<= 1) {
        #pragma unroll
        for (int k = 0; k < 8; ++k) acc[k] += __shfl_xor(acc[k], off, 64);
    }

    if (lane < 16) {
        float inv = 1.0f / (float)(deg > 0 ? deg : 1);
        uint4 o;
        o.x = pack_bf16x2(acc[0] * inv, acc[1] * inv);
        o.y = pack_bf16x2(acc[2] * inv, acc[3] * inv);
        o.z = pack_bf16x2(acc[4] * inv, acc[5] * inv);
        o.w = pack_bf16x2(acc[6] * inv, acc[7] * inv);
        *reinterpret_cast<uint4*>(A + ((size_t)node << 6) + (ch << 2)) = o;
    }
}

// ---------------------------------------------------------------------------
// Async staging of one 64x128 bf16 tile into LDS in A-frag order via
// global_load_lds: LDS dest is linear (base + lane*16); the frag-order
// permutation is applied to the per-lane GLOBAL source address instead.
// Slot s (16B granules): s = ((row>>4)*4 + ks)*64 + q*16 + (row&15),
// data chunk ch8 = ks*4 + q of row. Inverse: row = ((s>>8)<<4)|(s&15),
// ch8 = (((s>>6)&3)<<2)|((s>>4)&3). Per instruction, lanes 0/16/32/48
// read one row's contiguous 64B k-slice -> full HBM sectors consumed.
// ---------------------------------------------------------------------------
__device__ inline void stage_tile_async(
    const u16* __restrict__ Ain, u16* __restrict__ sDst,
    int base, int wave, int lane)
{
    #pragma unroll
    for (int it = 0; it < 4; ++it) {
        int s   = (wave * 4 + it) * 64 + lane;
        int row = ((s >> 8) << 4) | (s & 15);
        int ch8 = (((s >> 6) & 3) << 2) | ((s >> 4) & 3);
        int rowg = base + row; if (rowg > N_NODES - 1) rowg = N_NODES - 1;
        __builtin_amdgcn_global_load_lds(
            (const __attribute__((address_space(1))) void*)(Ain + ((size_t)rowg << 7) + (ch8 << 3)),
            (__attribute__((address_space(3))) void*)(sDst + ((wave * 4 + it) << 9)),
            16, 0, 0);
    }
}

// ---------------------------------------------------------------------------
// MFMA dual GEMM: out = [relu]( A1 @ W1 + bias [+ A2 @ W2] )
// bf16 output staged through LDS (padded stride 136 u16 = 17x16B) and
// written as coalesced uint4 rows; fp32 output (layer 3) stored direct
// (its 64B row-chunks are already sector-aligned).
// ---------------------------------------------------------------------------
__global__ __launch_bounds__(256) void mfma_gemm_kernel(
    const u16* __restrict__ A1, const u16* __restrict__ A2,
    const u16* __restrict__ W1p, const u16* __restrict__ W2p,
    const float* __restrict__ bias,
    u16* __restrict__ out16, float* __restrict__ out32, int do_relu)
{
    __shared__ __align__(16) u16 sAll[2 * 8192];    // 32 KB frag staging; reused for out-stage
    const int tid  = threadIdx.x;
    const int base = blockIdx.x * 64;
    const int nmats = (A2 != nullptr) ? 2 : 1;
    const int wave = tid >> 6;
    const int lane = tid & 63;

    stage_tile_async(A1, &sAll[0], base, wave, lane);
    if (nmats == 2) stage_tile_async(A2, &sAll[8192], base, wave, lane);
    __syncthreads();   // compiler drains vmcnt before s_barrier

    f32x4 acc[8];
    #pragma unroll
    for (int nt = 0; nt < 8; ++nt) acc[nt] = (f32x4){0.f, 0.f, 0.f, 0.f};

    for (int mat = 0; mat < nmats; ++mat) {
        const u16* Wp = mat ? W2p : W1p;
        const u16* sA = &sAll[mat * 8192];
        #pragma unroll
        for (int ks = 0; ks < 4; ++ks) {
            bf16x8 a = *reinterpret_cast<const bf16x8*>(sA + (((wave * 4 + ks) * 64 + lane) << 3));
            #pragma unroll
            for (int nt = 0; nt < 8; ++nt) {
                bf16x8 b = *reinterpret_cast<const bf16x8*>(Wp + (((nt * 4 + ks) * 64 + lane) << 3));
                acc[nt] = __builtin_amdgcn_mfma_f32_16x16x32_bf16(a, b, acc[nt], 0, 0, 0);
            }
        }
    }
    __syncthreads();   // all waves done reading frags; sAll reusable

    // ---- epilogue: bias+relu, stage bf16 rows in LDS, direct fp32 stores ----
    u16* sOut = sAll;                 // [64][136] u16 (8704 u16, fits easily)
    const int m = lane & 15;
    const int q = lane >> 4;
    #pragma unroll
    for (int nt = 0; nt < 8; ++nt) {
        int col = nt * 16 + m;
        float bv = bias[col];
        #pragma unroll
        for (int r = 0; r < 4; ++r) {
            float v = acc[nt][r] + bv;
            if (do_relu) v = fmaxf(v, 0.f);
            int row = wave * 16 + q * 4 + r;
            sOut[row * 136 + col] = f_to_bf16(v);
            if (out32) {
                int rowg = base + row;
                if (rowg < N_NODES) out32[((size_t)rowg << 7) + col] = v;
            }
        }
    }
    __syncthreads();

    if (out16) {
        #pragma unroll
        for (int it = 0; it < 4; ++it) {
            int c = it * 256 + tid;
            int row = c >> 4, ch = c & 15;
            int rowg = base + row;
            if (rowg < N_NODES)
                *reinterpret_cast<uint4*>(out16 + ((size_t)rowg << 7) + (ch << 3)) =
                    *reinterpret_cast<const uint4*>(sOut + row * 136 + (ch << 3));
        }
    }
}

// ---------------------------------------------------------------------------
// Fused MLP head: t = relu(h3 @ Wf1 + bf1) kept on-chip (written to LDS in
// A-frag order), then z = t @ Wf2 + bf2 and row-wise log_softmax in
// registers. Eliminates the 25.6 MB t write + 25.6 MB re-read.
// ---------------------------------------------------------------------------
__global__ __launch_bounds__(256) void mfma_head_kernel(
    const u16* __restrict__ h3,      // bf16 [N][128]
    const u16* __restrict__ Wf1p, const float* __restrict__ bf1,
    const u16* __restrict__ Wf2p, const float* __restrict__ bf2,
    float* __restrict__ out)         // [N][40]
{
    __shared__ __align__(16) u16 sA[8192];   // 16 KB
    const int tid  = threadIdx.x;
    const int base = blockIdx.x * 64;
    const int wave = tid >> 6;
    const int lane = tid & 63;

    stage_tile_async(h3, sA, base, wave, lane);
    __syncthreads();

    // ---- GEMM1: acc = h3 @ Wf1 ----
    f32x4 acc[8];
    #pragma unroll
    for (int nt = 0; nt < 8; ++nt) acc[nt] = (f32x4){0.f, 0.f, 0.f, 0.f};
    #pragma unroll
    for (int ks = 0; ks < 4; ++ks) {
        bf16x8 a = *reinterpret_cast<const bf16x8*>(sA + (((wave * 4 + ks) * 64 + lane) << 3));
        #pragma unroll
        for (int nt = 0; nt < 8; ++nt) {
            bf16x8 b = *reinterpret_cast<const bf16x8*>(Wf1p + (((nt * 4 + ks) * 64 + lane) << 3));
            acc[nt] = __builtin_amdgcn_mfma_f32_16x16x32_bf16(a, b, acc[nt], 0, 0, 0);
        }
    }
    __syncthreads();   // sA consumed; reuse for t

    // ---- t = relu(acc + bf1) -> sA in A-frag order ----
    // element (row, col): slot dc = (wave*4 + (col>>5))*64 + ((col>>3)&3)*16 + (row&15),
    // u16 index dc*8 + (col&7).  col = nt*16+m -> col>>5 = nt>>1,
    // (col>>3)&3 = (nt&1)*2 + (m>>3), col&7 = m&7.  row&15 = q*4+r.
    const int m = lane & 15;
    const int q = lane >> 4;
    #pragma unroll
    for (int nt = 0; nt < 8; ++nt) {
        int col = nt * 16 + m;
        float bv = bf1[col];
        #pragma unroll
        for (int r = 0; r < 4; ++r) {
            float v = fmaxf(acc[nt][r] + bv, 0.f);
            int dc = (wave * 4 + (nt >> 1)) * 64 + ((nt & 1) * 2 + (m >> 3)) * 16 + (q * 4 + r);
            sA[(dc << 3) | (m & 7)] = f_to_bf16(v);
        }
    }
    __syncthreads();

    // ---- GEMM2: z = t @ Wf2 (48-padded cols) ----
    f32x4 acc2[3];
    #pragma unroll
    for (int nt = 0; nt < 3; ++nt) acc2[nt] = (f32x4){0.f, 0.f, 0.f, 0.f};
    #pragma unroll
    for (int ks = 0; ks < 4; ++ks) {
        bf16x8 a = *reinterpret_cast<const bf16x8*>(sA + (((wave * 4 + ks) * 64 + lane) << 3));
        #pragma unroll
        for (int nt = 0; nt < 3; ++nt) {
            bf16x8 b = *reinterpret_cast<const bf16x8*>(Wf2p + (((nt * 4 + ks) * 64 + lane) << 3));
            acc2[nt] = __builtin_amdgcn_mfma_f32_16x16x32_bf16(a, b, acc2[nt], 0, 0, 0);
        }
    }

    // ---- log_softmax over 40 cols, quad-local shuffle reductions ----
    float z[3][4];
    float mx[4] = {-INFINITY, -INFINITY, -INFINITY, -INFINITY};
    #pragma unroll
    for (int nt = 0; nt < 3; ++nt) {
        int col = nt * 16 + m;
        bool valid = (col < ODIM);
        float bv = valid ? bf2[col] : 0.f;
        #pragma unroll
        for (int r = 0; r < 4; ++r) {
            z[nt][r] = acc2[nt][r] + bv;
            if (valid) mx[r] = fmaxf(mx[r], z[nt][r]);
        }
    }
    #pragma unroll
    for (int off = 1; off < 16; off <<= 1) {
        #pragma unroll
        for (int r = 0; r < 4; ++r) mx[r] = fmaxf(mx[r], __shfl_xor(mx[r], off, 16));
    }
    float sum[4] = {0.f, 0.f, 0.f, 0.f};
    #pragma unroll
    for (int nt = 0; nt < 3; ++nt) {
        int col = nt * 16 + m;
        if (col < ODIM) {
            #pragma unroll
            for (int r = 0; r < 4; ++r) sum[r] += expf(z[nt][r] - mx[r]);
        }
    }
    #pragma unroll
    for (int off = 1; off < 16; off <<= 1) {
        #pragma unroll
        for (int r = 0; r < 4; ++r) sum[r] += __shfl_xor(sum[r], off, 16);
    }
    float lse[4];
    #pragma unroll
    for (int r = 0; r < 4; ++r) lse[r] = logf(sum[r]) + mx[r];

    #pragma unroll
    for (int nt = 0; nt < 3; ++nt) {
        int col = nt * 16 + m;
        if (col >= ODIM) continue;
        #pragma unroll
        for (int r = 0; r < 4; ++r) {
            int rowg = base + wave * 16 + q * 4 + r;
            if (rowg >= N_NODES) continue;
            out[(size_t)rowg * ODIM + col] = z[nt][r] - lse[r];
        }
    }
}

// ---------------------------------------------------------------------------
extern "C" void kernel_launch(void* const* d_in, const int* in_sizes, int n_in,
                              void* d_out, int out_size, void* d_ws, size_t ws_size,
                              hipStream_t stream) {
    const float* x   = (const float*)d_in[0];
    const int*   ei  = (const int*)d_in[1];
    const int E = in_sizes[1] / 2;
    const int* src = ei;
    const int* dst = ei + E;

    const float* W1l = (const float*)d_in[2];
    const float* b1  = (const float*)d_in[3];
    const float* W1r = (const float*)d_in[4];
    const float* W2l = (const float*)d_in[5];
    const float* b2  = (const float*)d_in[6];
    const float* W2r = (const float*)d_in[7];
    const float* W3l = (const float*)d_in[8];
    const float* b3  = (const float*)d_in[9];
    const float* W3r = (const float*)d_in[10];
    const float* Wf1 = (const float*)d_in[11];
    const float* bf1 = (const float*)d_in[12];
    const float* Wf2 = (const float*)d_in[13];
    const float* bf2 = (const float*)d_in[14];

    float* out     = (float*)d_out;
    float* outTail = out + (size_t)N_NODES * ODIM;   // tuple part 2: h [N,128] fp32

    // CSR arrays live in d_out HEAD (overwritten by final softmax,
    // which launches after the last CSR use).
    int* ic = (int*)out;            // 100352 ints
    int* pc = ic + 100352;          // 100352 ints
    int* bs = pc + 100352;          // 1024 ints
    int* cs = bs + 1024;            // E ints  (total ~3.4 MB)

    // Workspace (u16 units): X16 | F16a | F16b | A16 | Wpk(7x16384) | Wf2p
    const size_t FEAT16 = (size_t)N_NODES * HDIM;   // 12.8M u16 = 25.6 MB
    u16* X16  = (u16*)d_ws;
    u16* F16a = X16  + FEAT16;
    u16* F16b = F16a + FEAT16;
    u16* A16  = F16b + FEAT16;
    u16* Wpk  = A16  + FEAT16;                      // 7*16384 u16
    u16* Wp_1l = Wpk + 0 * 16384;
    u16* Wp_1r = Wpk + 1 * 16384;
    u16* Wp_2l = Wpk + 2 * 16384;
    u16* Wp_2r = Wpk + 3 * 16384;
    u16* Wp_3l = Wpk + 4 * 16384;
    u16* Wp_3r = Wpk + 5 * 16384;
    u16* Wp_f1 = Wpk + 6 * 16384;
    u16* Wf2p  = Wpk + 7 * 16384;                   // 6144 u16

    const int gemmGrid   = (N_NODES + 63) / 64;   // 1563
    const int gatherGrid = N_NODES / 4;           // 25000
    const int edgeGrid   = (E + 255) / 256;       // 2500
    const int cvtGrid    = (N_NODES * HDIM / 2 + 255) / 256;  // 25000

    // ---- CSR build ----
    hipMemsetAsync(ic, 0, N_NODES * sizeof(int), stream);
    count_deg_kernel<<<edgeGrid, 256, 0, stream>>>(dst, ic, E);
    block_sum_kernel<<<NBLK, 256, 0, stream>>>(ic, bs, N_NODES);
    scan_bs_kernel<<<1, 512, 0, stream>>>(bs, NBLK);
    scan_block_kernel<<<NBLK, 256, 0, stream>>>(ic, bs, pc, N_NODES);
    fill_kernel<<<edgeGrid, 256, 0, stream>>>(src, dst, pc, cs, E);

    // ---- prep: x -> bf16, pack weights ----
    f2bf_kernel<<<cvtGrid, 256, 0, stream>>>((const float2*)x, (u32*)X16, N_NODES * HDIM / 2);
    WPtrs wp; wp.w[0] = W1l; wp.w[1] = W1r; wp.w[2] = W2l; wp.w[3] = W2r;
    wp.w[4] = W3l; wp.w[5] = W3r; wp.w[6] = Wf1;
    pack_w_kernel<<<dim3(64, 7), 256, 0, stream>>>(wp, Wpk);
    pack_wf2_kernel<<<24, 256, 0, stream>>>(Wf2, Wf2p);

    // ---- layer 1: X16 -> F16a ----
    gather_mean16_kernel<<<gatherGrid, 256, 0, stream>>>((const u32*)X16, cs, pc, ic, (u32*)A16);
    mfma_gemm_kernel<<<gemmGrid, 256, 0, stream>>>(A16, X16, Wp_1l, Wp_1r, b1, F16a, nullptr, 1);

    // ---- layer 2: F16a -> F16b ----
    gather_mean16_kernel<<<gatherGrid, 256, 0, stream>>>((const u32*)F16a, cs, pc, ic, (u32*)A16);
    mfma_gemm_kernel<<<gemmGrid, 256, 0, stream>>>(A16, F16a, Wp_2l, Wp_2r, b2, F16b, nullptr, 1);

    // ---- layer 3: F16b -> F16a (bf16) + outTail (fp32 h3), no relu ----
    gather_mean16_kernel<<<gatherGrid, 256, 0, stream>>>((const u32*)F16b, cs, pc, ic, (u32*)A16);
    mfma_gemm_kernel<<<gemmGrid, 256, 0, stream>>>(A16, F16b, Wp_3l, Wp_3r, b3, F16a, outTail, 0);

    // ---- fused MLP head + log_softmax -> out head (overwrites CSR debris) ----
    mfma_head_kernel<<<gemmGrid, 256, 0, stream>>>(F16a, Wp_f1, bf1, Wf2p, bf2, out);
}

// Round 2
// 421.092 us; speedup vs baseline: 1.1143x; 1.0146x over previous
//
#include <hip/hip_runtime.h>
#include <math.h>

#define N_NODES 100000
#define HDIM    128
#define ODIM    40
#define NBLK    ((N_NODES + 255) / 256)   // 391

typedef unsigned short u16;
typedef unsigned int   u32;
typedef short bf16x8 __attribute__((ext_vector_type(8)));   // 8 bf16 in 4 VGPRs
typedef float f32x4  __attribute__((ext_vector_type(4)));

// ---------------- bf16 helpers ----------------
__device__ inline float bf16lo_to_f(u32 v) {
    u32 u = v << 16; float f; __builtin_memcpy(&f, &u, 4); return f;
}
__device__ inline float bf16hi_to_f(u32 v) {
    u32 u = v & 0xffff0000u; float f; __builtin_memcpy(&f, &u, 4); return f;
}
__device__ inline u16 f_to_bf16(float f) {
    u32 u; __builtin_memcpy(&u, &f, 4);
    u32 r = (u + 0x7fffu + ((u >> 16) & 1u)) >> 16;   // round-nearest-even
    return (u16)r;
}
__device__ inline u32 pack_bf16x2(float a, float b) {
    return (u32)f_to_bf16(a) | ((u32)f_to_bf16(b) << 16);
}

// ---------------------------------------------------------------------------
// CSR build (counting sort by dst).
// ---------------------------------------------------------------------------
__global__ __launch_bounds__(256) void count_deg_kernel(
    const int* __restrict__ dst, int* __restrict__ ic, int E)
{
    int e = blockIdx.x * 256 + threadIdx.x;
    if (e < E) atomicAdd(ic + dst[e], 1);
}

__global__ __launch_bounds__(256) void block_sum_kernel(
    const int* __restrict__ ic, int* __restrict__ bs, int n)
{
    __shared__ int sm[256];
    int t = threadIdx.x;
    int i = blockIdx.x * 256 + t;
    sm[t] = (i < n) ? ic[i] : 0;
    __syncthreads();
    for (int s = 128; s > 0; s >>= 1) {
        if (t < s) sm[t] += sm[t + s];
        __syncthreads();
    }
    if (t == 0) bs[blockIdx.x] = sm[0];
}

__global__ __launch_bounds__(512) void scan_bs_kernel(int* __restrict__ bs, int nb)
{
    __shared__ int sm[512];
    int t = threadIdx.x;
    sm[t] = (t < nb) ? bs[t] : 0;
    __syncthreads();
    for (int off = 1; off < 512; off <<= 1) {
        int v = (t >= off) ? sm[t - off] : 0;
        __syncthreads();
        sm[t] += v;
        __syncthreads();
    }
    if (t < nb) bs[t] = (t == 0) ? 0 : sm[t - 1];
}

__global__ __launch_bounds__(256) void scan_block_kernel(
    const int* __restrict__ ic, const int* __restrict__ bs,
    int* __restrict__ pc, int n)
{
    __shared__ int sm[256];
    int t = threadIdx.x;
    int i = blockIdx.x * 256 + t;
    int v = (i < n) ? ic[i] : 0;
    sm[t] = v;
    __syncthreads();
    for (int off = 1; off < 256; off <<= 1) {
        int u = (t >= off) ? sm[t - off] : 0;
        __syncthreads();
        sm[t] += u;
        __syncthreads();
    }
    if (i < n) pc[i] = bs[blockIdx.x] + sm[t] - v;   // exclusive
}

__global__ __launch_bounds__(256) void fill_kernel(
    const int* __restrict__ src, const int* __restrict__ dst,
    int* __restrict__ pc, int* __restrict__ cs, int E)
{
    int e = blockIdx.x * 256 + threadIdx.x;
    if (e < E) {
        int p = atomicAdd(pc + dst[e], 1);
        cs[p] = src[e];
    }
}
// after fill: end(n) = pc[n], start(n) = pc[n] - ic[n]

// ---------------------------------------------------------------------------
// fp32 -> bf16 feature conversion (2 elements / thread).
// ---------------------------------------------------------------------------
__global__ __launch_bounds__(256) void f2bf_kernel(
    const float2* __restrict__ in, u32* __restrict__ out, int n2)
{
    int i = blockIdx.x * 256 + threadIdx.x;
    if (i < n2) { float2 v = in[i]; out[i] = pack_bf16x2(v.x, v.y); }
}

// ---------------------------------------------------------------------------
// Pack 128x128 fp32 weight matrices into bf16 MFMA B-fragment order:
//   frag (ntile, kslice): 64 lanes x 8 bf16, lane = q*16 + (n&15),
//   element j: B[k = kslice*32 + q*8 + j][n = ntile*16 + (n&15)]
// ---------------------------------------------------------------------------
struct WPtrs { const float* w[7]; };

__global__ __launch_bounds__(256) void pack_w_kernel(WPtrs p, u16* __restrict__ out)
{
    int mat = blockIdx.y;
    int e = blockIdx.x * 256 + threadIdx.x;      // 0..16383
    int k = e >> 7, n = e & 127;
    float v = p.w[mat][e];
    int nt = n >> 4, ks = k >> 5, q = (k >> 3) & 3, j = k & 7;
    int dst = mat * 16384 + (((nt * 4 + ks) * 64 + q * 16 + (n & 15)) << 3) + j;
    out[dst] = f_to_bf16(v);
}

// Pack Wf2 [128][40] into 128x48 (zero-padded) B-frag order: 3 ntiles x 4 ks.
__global__ __launch_bounds__(256) void pack_wf2_kernel(
    const float* __restrict__ Wf2, u16* __restrict__ outp)
{
    int e = blockIdx.x * 256 + threadIdx.x;      // 0..6143 (128*48)
    if (e >= 128 * 48) return;
    int k = e / 48, n = e - k * 48;
    float v = (n < ODIM) ? Wf2[k * ODIM + n] : 0.f;
    int nt = n >> 4, ks = k >> 5, q = (k >> 3) & 3, j = k & 7;
    outp[(((nt * 4 + ks) * 64 + q * 16 + (n & 15)) << 3) + j] = f_to_bf16(v);
}

// ---------------------------------------------------------------------------
// Mean-gather, one 16-lane group per node (16 nodes/block, 4/wave).
// Lane ch owns 16B chunk ch of the node's 256B feature row for ALL
// neighbors: no cross-lane shuffles, no butterfly reduction. Neighbor rows
// are pipelined depth-2 (c0/c1/n rotate, all static registers) so two row
// loads stay in flight per group; 4 independent chains per wave and full
// occupancy (no LDS, ~30 VGPR) maximize latency hiding.
// ---------------------------------------------------------------------------
__global__ __launch_bounds__(256) void gather_mean_grp_kernel(
    const u32* __restrict__ feat,    // [N][64] u32 (=128 bf16)
    const int* __restrict__ cs, const int* __restrict__ pc, const int* __restrict__ ic,
    u32* __restrict__ A)             // [N][64] u32
{
    const int grp  = threadIdx.x >> 4;            // 0..15
    const int ch   = threadIdx.x & 15;            // 16B chunk within row
    const int node = blockIdx.x * 16 + grp;       // grid*16 == N exactly
    const int end  = pc[node];
    const int deg  = ic[node];
    const int start = end - deg;

    const u32* fb = feat + (ch << 2);             // lane's chunk base

    float acc[8] = {0.f,0.f,0.f,0.f,0.f,0.f,0.f,0.f};
    const uint4 Z = {0u, 0u, 0u, 0u};

    if (deg > 0) {
        uint4 c0 = *reinterpret_cast<const uint4*>(fb + ((size_t)cs[start] << 6));
        uint4 c1 = (deg > 1)
            ? *reinterpret_cast<const uint4*>(fb + ((size_t)cs[start + 1] << 6)) : Z;
        for (int j = 0; j < deg; ++j) {
            uint4 n = (j + 2 < deg)
                ? *reinterpret_cast<const uint4*>(fb + ((size_t)cs[start + j + 2] << 6)) : Z;
            acc[0] += bf16lo_to_f(c0.x); acc[1] += bf16hi_to_f(c0.x);
            acc[2] += bf16lo_to_f(c0.y); acc[3] += bf16hi_to_f(c0.y);
            acc[4] += bf16lo_to_f(c0.z); acc[5] += bf16hi_to_f(c0.z);
            acc[6] += bf16lo_to_f(c0.w); acc[7] += bf16hi_to_f(c0.w);
            c0 = c1; c1 = n;
        }
    }

    float inv = 1.0f / (float)(deg > 0 ? deg : 1);
    uint4 o;
    o.x = pack_bf16x2(acc[0] * inv, acc[1] * inv);
    o.y = pack_bf16x2(acc[2] * inv, acc[3] * inv);
    o.z = pack_bf16x2(acc[4] * inv, acc[5] * inv);
    o.w = pack_bf16x2(acc[6] * inv, acc[7] * inv);
    *reinterpret_cast<uint4*>(A + ((size_t)node << 6) + (ch << 2)) = o;
}

// ---------------------------------------------------------------------------
// Async staging of one 64x128 bf16 tile into LDS in A-frag order via
// global_load_lds: LDS dest is linear (base + lane*16); the frag-order
// permutation is applied to the per-lane GLOBAL source address instead.
// ---------------------------------------------------------------------------
__device__ inline void stage_tile_async(
    const u16* __restrict__ Ain, u16* __restrict__ sDst,
    int base, int wave, int lane)
{
    #pragma unroll
    for (int it = 0; it < 4; ++it) {
        int s   = (wave * 4 + it) * 64 + lane;
        int row = ((s >> 8) << 4) | (s & 15);
        int ch8 = (((s >> 6) & 3) << 2) | ((s >> 4) & 3);
        int rowg = base + row; if (rowg > N_NODES - 1) rowg = N_NODES - 1;
        __builtin_amdgcn_global_load_lds(
            (const __attribute__((address_space(1))) void*)(Ain + ((size_t)rowg << 7) + (ch8 << 3)),
            (__attribute__((address_space(3))) void*)(sDst + ((wave * 4 + it) << 9)),
            16, 0, 0);
    }
}

// ---------------------------------------------------------------------------
// MFMA dual GEMM: out = [relu]( A1 @ W1 + bias [+ A2 @ W2] )
// bf16 output staged through LDS (padded stride 136 u16) and written as
// coalesced uint4 rows; fp32 output (layer 3) stored direct.
// ---------------------------------------------------------------------------
__global__ __launch_bounds__(256) void mfma_gemm_kernel(
    const u16* __restrict__ A1, const u16* __restrict__ A2,
    const u16* __restrict__ W1p, const u16* __restrict__ W2p,
    const float* __restrict__ bias,
    u16* __restrict__ out16, float* __restrict__ out32, int do_relu)
{
    __shared__ __align__(16) u16 sAll[2 * 8192];    // 32 KB frag staging; reused for out-stage
    const int tid  = threadIdx.x;
    const int base = blockIdx.x * 64;
    const int nmats = (A2 != nullptr) ? 2 : 1;
    const int wave = tid >> 6;
    const int lane = tid & 63;

    stage_tile_async(A1, &sAll[0], base, wave, lane);
    if (nmats == 2) stage_tile_async(A2, &sAll[8192], base, wave, lane);
    __syncthreads();   // compiler drains vmcnt before s_barrier

    f32x4 acc[8];
    #pragma unroll
    for (int nt = 0; nt < 8; ++nt) acc[nt] = (f32x4){0.f, 0.f, 0.f, 0.f};

    for (int mat = 0; mat < nmats; ++mat) {
        const u16* Wp = mat ? W2p : W1p;
        const u16* sA = &sAll[mat * 8192];
        #pragma unroll
        for (int ks = 0; ks < 4; ++ks) {
            bf16x8 a = *reinterpret_cast<const bf16x8*>(sA + (((wave * 4 + ks) * 64 + lane) << 3));
            #pragma unroll
            for (int nt = 0; nt < 8; ++nt) {
                bf16x8 b = *reinterpret_cast<const bf16x8*>(Wp + (((nt * 4 + ks) * 64 + lane) << 3));
                acc[nt] = __builtin_amdgcn_mfma_f32_16x16x32_bf16(a, b, acc[nt], 0, 0, 0);
            }
        }
    }
    __syncthreads();   // all waves done reading frags; sAll reusable

    // ---- epilogue: bias+relu, stage bf16 rows in LDS, direct fp32 stores ----
    u16* sOut = sAll;                 // [64][136] u16
    const int m = lane & 15;
    const int q = lane >> 4;
    #pragma unroll
    for (int nt = 0; nt < 8; ++nt) {
        int col = nt * 16 + m;
        float bv = bias[col];
        #pragma unroll
        for (int r = 0; r < 4; ++r) {
            float v = acc[nt][r] + bv;
            if (do_relu) v = fmaxf(v, 0.f);
            int row = wave * 16 + q * 4 + r;
            sOut[row * 136 + col] = f_to_bf16(v);
            if (out32) {
                int rowg = base + row;
                if (rowg < N_NODES) out32[((size_t)rowg << 7) + col] = v;
            }
        }
    }
    __syncthreads();

    if (out16) {
        #pragma unroll
        for (int it = 0; it < 4; ++it) {
            int c = it * 256 + tid;
            int row = c >> 4, ch = c & 15;
            int rowg = base + row;
            if (rowg < N_NODES)
                *reinterpret_cast<uint4*>(out16 + ((size_t)rowg << 7) + (ch << 3)) =
                    *reinterpret_cast<const uint4*>(sOut + row * 136 + (ch << 3));
        }
    }
}

// ---------------------------------------------------------------------------
// Fused MLP head: t = relu(h3 @ Wf1 + bf1) kept on-chip (written to LDS in
// A-frag order), then z = t @ Wf2 + bf2 and row-wise log_softmax in
// registers.
// ---------------------------------------------------------------------------
__global__ __launch_bounds__(256) void mfma_head_kernel(
    const u16* __restrict__ h3,      // bf16 [N][128]
    const u16* __restrict__ Wf1p, const float* __restrict__ bf1,
    const u16* __restrict__ Wf2p, const float* __restrict__ bf2,
    float* __restrict__ out)         // [N][40]
{
    __shared__ __align__(16) u16 sA[8192];   // 16 KB
    const int tid  = threadIdx.x;
    const int base = blockIdx.x * 64;
    const int wave = tid >> 6;
    const int lane = tid & 63;

    stage_tile_async(h3, sA, base, wave, lane);
    __syncthreads();

    // ---- GEMM1: acc = h3 @ Wf1 ----
    f32x4 acc[8];
    #pragma unroll
    for (int nt = 0; nt < 8; ++nt) acc[nt] = (f32x4){0.f, 0.f, 0.f, 0.f};
    #pragma unroll
    for (int ks = 0; ks < 4; ++ks) {
        bf16x8 a = *reinterpret_cast<const bf16x8*>(sA + (((wave * 4 + ks) * 64 + lane) << 3));
        #pragma unroll
        for (int nt = 0; nt < 8; ++nt) {
            bf16x8 b = *reinterpret_cast<const bf16x8*>(Wf1p + (((nt * 4 + ks) * 64 + lane) << 3));
            acc[nt] = __builtin_amdgcn_mfma_f32_16x16x32_bf16(a, b, acc[nt], 0, 0, 0);
        }
    }
    __syncthreads();   // sA consumed; reuse for t

    // ---- t = relu(acc + bf1) -> sA in A-frag order ----
    const int m = lane & 15;
    const int q = lane >> 4;
    #pragma unroll
    for (int nt = 0; nt < 8; ++nt) {
        int col = nt * 16 + m;
        float bv = bf1[col];
        #pragma unroll
        for (int r = 0; r < 4; ++r) {
            float v = fmaxf(acc[nt][r] + bv, 0.f);
            int dc = (wave * 4 + (nt >> 1)) * 64 + ((nt & 1) * 2 + (m >> 3)) * 16 + (q * 4 + r);
            sA[(dc << 3) | (m & 7)] = f_to_bf16(v);
        }
    }
    __syncthreads();

    // ---- GEMM2: z = t @ Wf2 (48-padded cols) ----
    f32x4 acc2[3];
    #pragma unroll
    for (int nt = 0; nt < 3; ++nt) acc2[nt] = (f32x4){0.f, 0.f, 0.f, 0.f};
    #pragma unroll
    for (int ks = 0; ks < 4; ++ks) {
        bf16x8 a = *reinterpret_cast<const bf16x8*>(sA + (((wave * 4 + ks) * 64 + lane) << 3));
        #pragma unroll
        for (int nt = 0; nt < 3; ++nt) {
            bf16x8 b = *reinterpret_cast<const bf16x8*>(Wf2p + (((nt * 4 + ks) * 64 + lane) << 3));
            acc2[nt] = __builtin_amdgcn_mfma_f32_16x16x32_bf16(a, b, acc2[nt], 0, 0, 0);
        }
    }

    // ---- log_softmax over 40 cols, quad-local shuffle reductions ----
    float z[3][4];
    float mx[4] = {-INFINITY, -INFINITY, -INFINITY, -INFINITY};
    #pragma unroll
    for (int nt = 0; nt < 3; ++nt) {
        int col = nt * 16 + m;
        bool valid = (col < ODIM);
        float bv = valid ? bf2[col] : 0.f;
        #pragma unroll
        for (int r = 0; r < 4; ++r) {
            z[nt][r] = acc2[nt][r] + bv;
            if (valid) mx[r] = fmaxf(mx[r], z[nt][r]);
        }
    }
    #pragma unroll
    for (int off = 1; off < 16; off <<= 1) {
        #pragma unroll
        for (int r = 0; r < 4; ++r) mx[r] = fmaxf(mx[r], __shfl_xor(mx[r], off, 16));
    }
    float sum[4] = {0.f, 0.f, 0.f, 0.f};
    #pragma unroll
    for (int nt = 0; nt < 3; ++nt) {
        int col = nt * 16 + m;
        if (col < ODIM) {
            #pragma unroll
            for (int r = 0; r < 4; ++r) sum[r] += expf(z[nt][r] - mx[r]);
        }
    }
    #pragma unroll
    for (int off = 1; off < 16; off <<= 1) {
        #pragma unroll
        for (int r = 0; r < 4; ++r) sum[r] += __shfl_xor(sum[r], off, 16);
    }
    float lse[4];
    #pragma unroll
    for (int r = 0; r < 4; ++r) lse[r] = logf(sum[r]) + mx[r];

    #pragma unroll
    for (int nt = 0; nt < 3; ++nt) {
        int col = nt * 16 + m;
        if (col >= ODIM) continue;
        #pragma unroll
        for (int r = 0; r < 4; ++r) {
            int rowg = base + wave * 16 + q * 4 + r;
            if (rowg >= N_NODES) continue;
            out[(size_t)rowg * ODIM + col] = z[nt][r] - lse[r];
        }
    }
}

// ---------------------------------------------------------------------------
extern "C" void kernel_launch(void* const* d_in, const int* in_sizes, int n_in,
                              void* d_out, int out_size, void* d_ws, size_t ws_size,
                              hipStream_t stream) {
    const float* x   = (const float*)d_in[0];
    const int*   ei  = (const int*)d_in[1];
    const int E = in_sizes[1] / 2;
    const int* src = ei;
    const int* dst = ei + E;

    const float* W1l = (const float*)d_in[2];
    const float* b1  = (const float*)d_in[3];
    const float* W1r = (const float*)d_in[4];
    const float* W2l = (const float*)d_in[5];
    const float* b2  = (const float*)d_in[6];
    const float* W2r = (const float*)d_in[7];
    const float* W3l = (const float*)d_in[8];
    const float* b3  = (const float*)d_in[9];
    const float* W3r = (const float*)d_in[10];
    const float* Wf1 = (const float*)d_in[11];
    const float* bf1 = (const float*)d_in[12];
    const float* Wf2 = (const float*)d_in[13];
    const float* bf2 = (const float*)d_in[14];

    float* out     = (float*)d_out;
    float* outTail = out + (size_t)N_NODES * ODIM;   // tuple part 2: h [N,128] fp32

    // CSR arrays live in d_out HEAD (overwritten by final softmax,
    // which launches after the last CSR use).
    int* ic = (int*)out;            // 100352 ints
    int* pc = ic + 100352;          // 100352 ints
    int* bs = pc + 100352;          // 1024 ints
    int* cs = bs + 1024;            // E ints  (total ~3.4 MB)

    // Workspace (u16 units): X16 | F16a | F16b | A16 | Wpk(7x16384) | Wf2p
    const size_t FEAT16 = (size_t)N_NODES * HDIM;   // 12.8M u16 = 25.6 MB
    u16* X16  = (u16*)d_ws;
    u16* F16a = X16  + FEAT16;
    u16* F16b = F16a + FEAT16;
    u16* A16  = F16b + FEAT16;
    u16* Wpk  = A16  + FEAT16;                      // 7*16384 u16
    u16* Wp_1l = Wpk + 0 * 16384;
    u16* Wp_1r = Wpk + 1 * 16384;
    u16* Wp_2l = Wpk + 2 * 16384;
    u16* Wp_2r = Wpk + 3 * 16384;
    u16* Wp_3l = Wpk + 4 * 16384;
    u16* Wp_3r = Wpk + 5 * 16384;
    u16* Wp_f1 = Wpk + 6 * 16384;
    u16* Wf2p  = Wpk + 7 * 16384;                   // 6144 u16

    const int gemmGrid   = (N_NODES + 63) / 64;   // 1563
    const int gatherGrid = N_NODES / 16;          // 6250 (16 nodes/block, exact)
    const int edgeGrid   = (E + 255) / 256;       // 2500
    const int cvtGrid    = (N_NODES * HDIM / 2 + 255) / 256;  // 25000

    // ---- CSR build ----
    hipMemsetAsync(ic, 0, N_NODES * sizeof(int), stream);
    count_deg_kernel<<<edgeGrid, 256, 0, stream>>>(dst, ic, E);
    block_sum_kernel<<<NBLK, 256, 0, stream>>>(ic, bs, N_NODES);
    scan_bs_kernel<<<1, 512, 0, stream>>>(bs, NBLK);
    scan_block_kernel<<<NBLK, 256, 0, stream>>>(ic, bs, pc, N_NODES);
    fill_kernel<<<edgeGrid, 256, 0, stream>>>(src, dst, pc, cs, E);

    // ---- prep: x -> bf16, pack weights ----
    f2bf_kernel<<<cvtGrid, 256, 0, stream>>>((const float2*)x, (u32*)X16, N_NODES * HDIM / 2);
    WPtrs wp; wp.w[0] = W1l; wp.w[1] = W1r; wp.w[2] = W2l; wp.w[3] = W2r;
    wp.w[4] = W3l; wp.w[5] = W3r; wp.w[6] = Wf1;
    pack_w_kernel<<<dim3(64, 7), 256, 0, stream>>>(wp, Wpk);
    pack_wf2_kernel<<<24, 256, 0, stream>>>(Wf2, Wf2p);

    // ---- layer 1: X16 -> F16a ----
    gather_mean_grp_kernel<<<gatherGrid, 256, 0, stream>>>((const u32*)X16, cs, pc, ic, (u32*)A16);
    mfma_gemm_kernel<<<gemmGrid, 256, 0, stream>>>(A16, X16, Wp_1l, Wp_1r, b1, F16a, nullptr, 1);

    // ---- layer 2: F16a -> F16b ----
    gather_mean_grp_kernel<<<gatherGrid, 256, 0, stream>>>((const u32*)F16a, cs, pc, ic, (u32*)A16);
    mfma_gemm_kernel<<<gemmGrid, 256, 0, stream>>>(A16, F16a, Wp_2l, Wp_2r, b2, F16b, nullptr, 1);

    // ---- layer 3: F16b -> F16a (bf16) + outTail (fp32 h3), no relu ----
    gather_mean_grp_kernel<<<gatherGrid, 256, 0, stream>>>((const u32*)F16b, cs, pc, ic, (u32*)A16);
    mfma_gemm_kernel<<<gemmGrid, 256, 0, stream>>>(A16, F16b, Wp_3l, Wp_3r, b3, F16a, outTail, 0);

    // ---- fused MLP head + log_softmax -> out head (overwrites CSR debris) ----
    mfma_head_kernel<<<gemmGrid, 256, 0, stream>>>(F16a, Wp_f1, bf1, Wf2p, bf2, out);
}

// Round 3
// 402.128 us; speedup vs baseline: 1.1668x; 1.0472x over previous
//
#include <hip/hip_runtime.h>
#include <math.h>

#define N_NODES 100000
#define HDIM    128
#define ODIM    40
#define NBLK    ((N_NODES + 255) / 256)   // 391

typedef unsigned short u16;
typedef unsigned int   u32;
typedef short bf16x8 __attribute__((ext_vector_type(8)));   // 8 bf16 in 4 VGPRs
typedef float f32x4  __attribute__((ext_vector_type(4)));

// ---------------- bf16 helpers ----------------
__device__ inline float bf16lo_to_f(u32 v) {
    u32 u = v << 16; float f; __builtin_memcpy(&f, &u, 4); return f;
}
__device__ inline float bf16hi_to_f(u32 v) {
    u32 u = v & 0xffff0000u; float f; __builtin_memcpy(&f, &u, 4); return f;
}
__device__ inline u16 f_to_bf16(float f) {
    u32 u; __builtin_memcpy(&u, &f, 4);
    u32 r = (u + 0x7fffu + ((u >> 16) & 1u)) >> 16;   // round-nearest-even
    return (u16)r;
}
__device__ inline u32 pack_bf16x2(float a, float b) {
    return (u32)f_to_bf16(a) | ((u32)f_to_bf16(b) << 16);
}

// ---------------------------------------------------------------------------
// CSR build (counting sort by dst).
// ---------------------------------------------------------------------------
__global__ __launch_bounds__(256) void count_deg_kernel(
    const int* __restrict__ dst, int* __restrict__ ic, int E)
{
    int e = blockIdx.x * 256 + threadIdx.x;
    if (e < E) atomicAdd(ic + dst[e], 1);
}

__global__ __launch_bounds__(256) void block_sum_kernel(
    const int* __restrict__ ic, int* __restrict__ bs, int n)
{
    __shared__ int sm[256];
    int t = threadIdx.x;
    int i = blockIdx.x * 256 + t;
    sm[t] = (i < n) ? ic[i] : 0;
    __syncthreads();
    for (int s = 128; s > 0; s >>= 1) {
        if (t < s) sm[t] += sm[t + s];
        __syncthreads();
    }
    if (t == 0) bs[blockIdx.x] = sm[0];
}

__global__ __launch_bounds__(512) void scan_bs_kernel(int* __restrict__ bs, int nb)
{
    __shared__ int sm[512];
    int t = threadIdx.x;
    sm[t] = (t < nb) ? bs[t] : 0;
    __syncthreads();
    for (int off = 1; off < 512; off <<= 1) {
        int v = (t >= off) ? sm[t - off] : 0;
        __syncthreads();
        sm[t] += v;
        __syncthreads();
    }
    if (t < nb) bs[t] = (t == 0) ? 0 : sm[t - 1];
}

__global__ __launch_bounds__(256) void scan_block_kernel(
    const int* __restrict__ ic, const int* __restrict__ bs,
    int* __restrict__ pc, int n)
{
    __shared__ int sm[256];
    int t = threadIdx.x;
    int i = blockIdx.x * 256 + t;
    int v = (i < n) ? ic[i] : 0;
    sm[t] = v;
    __syncthreads();
    for (int off = 1; off < 256; off <<= 1) {
        int u = (t >= off) ? sm[t - off] : 0;
        __syncthreads();
        sm[t] += u;
        __syncthreads();
    }
    if (i < n) pc[i] = bs[blockIdx.x] + sm[t] - v;   // exclusive
}

__global__ __launch_bounds__(256) void fill_kernel(
    const int* __restrict__ src, const int* __restrict__ dst,
    int* __restrict__ pc, int* __restrict__ cs, int E)
{
    int e = blockIdx.x * 256 + threadIdx.x;
    if (e < E) {
        int p = atomicAdd(pc + dst[e], 1);
        cs[p] = src[e];
    }
}
// after fill: end(n) = pc[n], start(n) = pc[n] - ic[n]

// ---------------------------------------------------------------------------
// fp32 -> bf16 feature conversion (2 elements / thread).
// ---------------------------------------------------------------------------
__global__ __launch_bounds__(256) void f2bf_kernel(
    const float2* __restrict__ in, u32* __restrict__ out, int n2)
{
    int i = blockIdx.x * 256 + threadIdx.x;
    if (i < n2) { float2 v = in[i]; out[i] = pack_bf16x2(v.x, v.y); }
}

// ---------------------------------------------------------------------------
// Pack 128x128 fp32 weight matrices into bf16 MFMA B-fragment order:
//   frag (ntile, kslice): 64 lanes x 8 bf16, lane = q*16 + (n&15),
//   element j: B[k = kslice*32 + q*8 + j][n = ntile*16 + (n&15)]
// ---------------------------------------------------------------------------
struct WPtrs { const float* w[7]; };

__global__ __launch_bounds__(256) void pack_w_kernel(WPtrs p, u16* __restrict__ out)
{
    int mat = blockIdx.y;
    int e = blockIdx.x * 256 + threadIdx.x;      // 0..16383
    int k = e >> 7, n = e & 127;
    float v = p.w[mat][e];
    int nt = n >> 4, ks = k >> 5, q = (k >> 3) & 3, j = k & 7;
    int dst = mat * 16384 + (((nt * 4 + ks) * 64 + q * 16 + (n & 15)) << 3) + j;
    out[dst] = f_to_bf16(v);
}

// Pack Wf2 [128][40] into 128x48 (zero-padded) B-frag order: 3 ntiles x 4 ks.
__global__ __launch_bounds__(256) void pack_wf2_kernel(
    const float* __restrict__ Wf2, u16* __restrict__ outp)
{
    int e = blockIdx.x * 256 + threadIdx.x;      // 0..6143 (128*48)
    if (e >= 128 * 48) return;
    int k = e / 48, n = e - k * 48;
    float v = (n < ODIM) ? Wf2[k * ODIM + n] : 0.f;
    int nt = n >> 4, ks = k >> 5, q = (k >> 3) & 3, j = k & 7;
    outp[(((nt * 4 + ks) * 64 + q * 16 + (n & 15)) << 3) + j] = f_to_bf16(v);
}

// ---------------------------------------------------------------------------
// Mean-gather, one 16-lane group per node (16 nodes/block, 4/wave).
// Near the random-access throughput bound of the L2/L3 system; unchanged.
// ---------------------------------------------------------------------------
__global__ __launch_bounds__(256) void gather_mean_grp_kernel(
    const u32* __restrict__ feat,    // [N][64] u32 (=128 bf16)
    const int* __restrict__ cs, const int* __restrict__ pc, const int* __restrict__ ic,
    u32* __restrict__ A)             // [N][64] u32
{
    const int grp  = threadIdx.x >> 4;            // 0..15
    const int ch   = threadIdx.x & 15;            // 16B chunk within row
    const int node = blockIdx.x * 16 + grp;       // grid*16 == N exactly
    const int end  = pc[node];
    const int deg  = ic[node];
    const int start = end - deg;

    const u32* fb = feat + (ch << 2);             // lane's chunk base

    float acc[8] = {0.f,0.f,0.f,0.f,0.f,0.f,0.f,0.f};
    const uint4 Z = {0u, 0u, 0u, 0u};

    if (deg > 0) {
        uint4 c0 = *reinterpret_cast<const uint4*>(fb + ((size_t)cs[start] << 6));
        uint4 c1 = (deg > 1)
            ? *reinterpret_cast<const uint4*>(fb + ((size_t)cs[start + 1] << 6)) : Z;
        for (int j = 0; j < deg; ++j) {
            uint4 n = (j + 2 < deg)
                ? *reinterpret_cast<const uint4*>(fb + ((size_t)cs[start + j + 2] << 6)) : Z;
            acc[0] += bf16lo_to_f(c0.x); acc[1] += bf16hi_to_f(c0.x);
            acc[2] += bf16lo_to_f(c0.y); acc[3] += bf16hi_to_f(c0.y);
            acc[4] += bf16lo_to_f(c0.z); acc[5] += bf16hi_to_f(c0.z);
            acc[6] += bf16lo_to_f(c0.w); acc[7] += bf16hi_to_f(c0.w);
            c0 = c1; c1 = n;
        }
    }

    float inv = 1.0f / (float)(deg > 0 ? deg : 1);
    uint4 o;
    o.x = pack_bf16x2(acc[0] * inv, acc[1] * inv);
    o.y = pack_bf16x2(acc[2] * inv, acc[3] * inv);
    o.z = pack_bf16x2(acc[4] * inv, acc[5] * inv);
    o.w = pack_bf16x2(acc[6] * inv, acc[7] * inv);
    *reinterpret_cast<uint4*>(A + ((size_t)node << 6) + (ch << 2)) = o;
}

// ---------------------------------------------------------------------------
// MFMA dual GEMM v3: out = [relu]( A1 @ W1 + bias [+ A2 @ W2] )
// - W staged to LDS once per block (one mat at a time, 32 KB linear copy via
//   global_load_lds); b-fragments via ds_read_b128, never per-MFMA global.
// - A-fragments loaded DIRECTLY to registers (16B contiguous row chunks,
//   64B/row segments), fully prefetched before the barrier. No A-LDS stage.
// - 128 rows/block (2 row-tiles/wave): W staging + traffic amortized 2x.
// - Epilogue: bf16 rows staged in the (reused) LDS buffer, stored as
//   coalesced uint4; fp32 (layer 3) stored direct.
// ---------------------------------------------------------------------------
__global__ __launch_bounds__(256) void mfma_gemm_kernel(
    const u16* __restrict__ A1, const u16* __restrict__ A2,
    const u16* __restrict__ W1p, const u16* __restrict__ W2p,
    const float* __restrict__ bias,
    u16* __restrict__ out16, float* __restrict__ out32, int do_relu)
{
    __shared__ __align__(16) u16 sBuf[128 * 136];   // 34.8 KB: W frags, then out staging
    const int tid  = threadIdx.x;
    const int wave = tid >> 6;
    const int lane = tid & 63;
    const int m = lane & 15;
    const int q = lane >> 4;
    const int base = blockIdx.x * 128;

    int row0 = base + wave * 16 + m;        if (row0 > N_NODES - 1) row0 = N_NODES - 1;
    int row1 = base + (wave + 4) * 16 + m;  if (row1 > N_NODES - 1) row1 = N_NODES - 1;

    f32x4 acc0[8], acc1[8];
    #pragma unroll
    for (int nt = 0; nt < 8; ++nt) {
        acc0[nt] = (f32x4){0.f, 0.f, 0.f, 0.f};
        acc1[nt] = (f32x4){0.f, 0.f, 0.f, 0.f};
    }

    // ---- mat 0: prefetch a-frags to regs, stage W1 to LDS ----
    bf16x8 a0[4], a1[4];
    #pragma unroll
    for (int ks = 0; ks < 4; ++ks) {
        a0[ks] = *reinterpret_cast<const bf16x8*>(A1 + ((size_t)row0 << 7) + ((ks * 4 + q) << 3));
        a1[ks] = *reinterpret_cast<const bf16x8*>(A1 + ((size_t)row1 << 7) + ((ks * 4 + q) << 3));
    }
    #pragma unroll
    for (int it = 0; it < 8; ++it) {
        int off = (it * 4 + wave) << 9;             // 512 u16 = 1 KB chunks
        __builtin_amdgcn_global_load_lds(
            (const __attribute__((address_space(1))) void*)(W1p + off + (lane << 3)),
            (__attribute__((address_space(3))) void*)(sBuf + off), 16, 0, 0);
    }
    __syncthreads();

    #pragma unroll
    for (int ks = 0; ks < 4; ++ks) {
        #pragma unroll
        for (int nt = 0; nt < 8; ++nt) {
            bf16x8 b = *reinterpret_cast<const bf16x8*>(sBuf + (((nt * 4 + ks) * 64 + lane) << 3));
            acc0[nt] = __builtin_amdgcn_mfma_f32_16x16x32_bf16(a0[ks], b, acc0[nt], 0, 0, 0);
            acc1[nt] = __builtin_amdgcn_mfma_f32_16x16x32_bf16(a1[ks], b, acc1[nt], 0, 0, 0);
        }
    }

    if (A2 != nullptr) {
        __syncthreads();   // all waves done reading W1 frags
        #pragma unroll
        for (int ks = 0; ks < 4; ++ks) {
            a0[ks] = *reinterpret_cast<const bf16x8*>(A2 + ((size_t)row0 << 7) + ((ks * 4 + q) << 3));
            a1[ks] = *reinterpret_cast<const bf16x8*>(A2 + ((size_t)row1 << 7) + ((ks * 4 + q) << 3));
        }
        #pragma unroll
        for (int it = 0; it < 8; ++it) {
            int off = (it * 4 + wave) << 9;
            __builtin_amdgcn_global_load_lds(
                (const __attribute__((address_space(1))) void*)(W2p + off + (lane << 3)),
                (__attribute__((address_space(3))) void*)(sBuf + off), 16, 0, 0);
        }
        __syncthreads();

        #pragma unroll
        for (int ks = 0; ks < 4; ++ks) {
            #pragma unroll
            for (int nt = 0; nt < 8; ++nt) {
                bf16x8 b = *reinterpret_cast<const bf16x8*>(sBuf + (((nt * 4 + ks) * 64 + lane) << 3));
                acc0[nt] = __builtin_amdgcn_mfma_f32_16x16x32_bf16(a0[ks], b, acc0[nt], 0, 0, 0);
                acc1[nt] = __builtin_amdgcn_mfma_f32_16x16x32_bf16(a1[ks], b, acc1[nt], 0, 0, 0);
            }
        }
    }
    __syncthreads();   // W frags dead; sBuf reusable for out staging

    // ---- epilogue ----
    #pragma unroll
    for (int nt = 0; nt < 8; ++nt) {
        int col = nt * 16 + m;
        float bv = bias[col];
        #pragma unroll
        for (int r = 0; r < 4; ++r) {
            float v0 = acc0[nt][r] + bv;
            float v1 = acc1[nt][r] + bv;
            if (do_relu) { v0 = fmaxf(v0, 0.f); v1 = fmaxf(v1, 0.f); }
            int rl0 = wave * 16 + q * 4 + r;
            int rl1 = rl0 + 64;
            sBuf[rl0 * 136 + col] = f_to_bf16(v0);
            sBuf[rl1 * 136 + col] = f_to_bf16(v1);
            if (out32) {
                int rg0 = base + rl0, rg1 = base + rl1;
                if (rg0 < N_NODES) out32[((size_t)rg0 << 7) + col] = v0;
                if (rg1 < N_NODES) out32[((size_t)rg1 << 7) + col] = v1;
            }
        }
    }
    __syncthreads();

    if (out16) {
        #pragma unroll
        for (int it = 0; it < 8; ++it) {
            int c = it * 256 + tid;
            int row = c >> 4, ch = c & 15;
            int rowg = base + row;
            if (rowg < N_NODES)
                *reinterpret_cast<uint4*>(out16 + ((size_t)rowg << 7) + (ch << 3)) =
                    *reinterpret_cast<const uint4*>(sBuf + row * 136 + (ch << 3));
        }
    }
}

// ---------------------------------------------------------------------------
// Fused MLP head: t = relu(h3 @ Wf1 + bf1) kept on-chip (t written to the
// reused Wf1 LDS region in A-frag order), then z = t @ Wf2 + bf2 and
// row-wise log_softmax in registers. Both W mats staged to LDS; h3 a-frags
// loaded direct to registers.
// ---------------------------------------------------------------------------
__global__ __launch_bounds__(256) void mfma_head_kernel(
    const u16* __restrict__ h3,      // bf16 [N][128]
    const u16* __restrict__ Wf1p, const float* __restrict__ bf1,
    const u16* __restrict__ Wf2p, const float* __restrict__ bf2,
    float* __restrict__ out)         // [N][40]
{
    __shared__ __align__(16) u16 sW1[16384];   // 32 KB; first 16 KB reused for t
    __shared__ __align__(16) u16 sW2[6144];    // 12 KB
    const int tid  = threadIdx.x;
    const int base = blockIdx.x * 64;
    const int wave = tid >> 6;
    const int lane = tid & 63;
    const int m = lane & 15;
    const int q = lane >> 4;

    int row = base + wave * 16 + m; if (row > N_NODES - 1) row = N_NODES - 1;

    bf16x8 a[4];
    #pragma unroll
    for (int ks = 0; ks < 4; ++ks)
        a[ks] = *reinterpret_cast<const bf16x8*>(h3 + ((size_t)row << 7) + ((ks * 4 + q) << 3));

    #pragma unroll
    for (int it = 0; it < 8; ++it) {
        int off = (it * 4 + wave) << 9;
        __builtin_amdgcn_global_load_lds(
            (const __attribute__((address_space(1))) void*)(Wf1p + off + (lane << 3)),
            (__attribute__((address_space(3))) void*)(sW1 + off), 16, 0, 0);
    }
    #pragma unroll
    for (int it = 0; it < 3; ++it) {
        int off = (it * 4 + wave) << 9;
        __builtin_amdgcn_global_load_lds(
            (const __attribute__((address_space(1))) void*)(Wf2p + off + (lane << 3)),
            (__attribute__((address_space(3))) void*)(sW2 + off), 16, 0, 0);
    }
    __syncthreads();

    // ---- GEMM1: acc = h3 @ Wf1 ----
    f32x4 acc[8];
    #pragma unroll
    for (int nt = 0; nt < 8; ++nt) acc[nt] = (f32x4){0.f, 0.f, 0.f, 0.f};
    #pragma unroll
    for (int ks = 0; ks < 4; ++ks) {
        #pragma unroll
        for (int nt = 0; nt < 8; ++nt) {
            bf16x8 b = *reinterpret_cast<const bf16x8*>(sW1 + (((nt * 4 + ks) * 64 + lane) << 3));
            acc[nt] = __builtin_amdgcn_mfma_f32_16x16x32_bf16(a[ks], b, acc[nt], 0, 0, 0);
        }
    }
    __syncthreads();   // sW1 frags consumed; reuse for t

    // ---- t = relu(acc + bf1) -> sW1 (A-frag order) ----
    #pragma unroll
    for (int nt = 0; nt < 8; ++nt) {
        int col = nt * 16 + m;
        float bv = bf1[col];
        #pragma unroll
        for (int r = 0; r < 4; ++r) {
            float v = fmaxf(acc[nt][r] + bv, 0.f);
            int dc = (wave * 4 + (nt >> 1)) * 64 + ((nt & 1) * 2 + (m >> 3)) * 16 + (q * 4 + r);
            sW1[(dc << 3) | (m & 7)] = f_to_bf16(v);
        }
    }
    __syncthreads();

    // ---- GEMM2: z = t @ Wf2 (48-padded cols) ----
    f32x4 acc2[3];
    #pragma unroll
    for (int nt = 0; nt < 3; ++nt) acc2[nt] = (f32x4){0.f, 0.f, 0.f, 0.f};
    #pragma unroll
    for (int ks = 0; ks < 4; ++ks) {
        bf16x8 a2 = *reinterpret_cast<const bf16x8*>(sW1 + (((wave * 4 + ks) * 64 + lane) << 3));
        #pragma unroll
        for (int nt = 0; nt < 3; ++nt) {
            bf16x8 b = *reinterpret_cast<const bf16x8*>(sW2 + (((nt * 4 + ks) * 64 + lane) << 3));
            acc2[nt] = __builtin_amdgcn_mfma_f32_16x16x32_bf16(a2, b, acc2[nt], 0, 0, 0);
        }
    }

    // ---- log_softmax over 40 cols, quad-local shuffle reductions ----
    float z[3][4];
    float mx[4] = {-INFINITY, -INFINITY, -INFINITY, -INFINITY};
    #pragma unroll
    for (int nt = 0; nt < 3; ++nt) {
        int col = nt * 16 + m;
        bool valid = (col < ODIM);
        float bv = valid ? bf2[col] : 0.f;
        #pragma unroll
        for (int r = 0; r < 4; ++r) {
            z[nt][r] = acc2[nt][r] + bv;
            if (valid) mx[r] = fmaxf(mx[r], z[nt][r]);
        }
    }
    #pragma unroll
    for (int off = 1; off < 16; off <<= 1) {
        #pragma unroll
        for (int r = 0; r < 4; ++r) mx[r] = fmaxf(mx[r], __shfl_xor(mx[r], off, 16));
    }
    float sum[4] = {0.f, 0.f, 0.f, 0.f};
    #pragma unroll
    for (int nt = 0; nt < 3; ++nt) {
        int col = nt * 16 + m;
        if (col < ODIM) {
            #pragma unroll
            for (int r = 0; r < 4; ++r) sum[r] += expf(z[nt][r] - mx[r]);
        }
    }
    #pragma unroll
    for (int off = 1; off < 16; off <<= 1) {
        #pragma unroll
        for (int r = 0; r < 4; ++r) sum[r] += __shfl_xor(sum[r], off, 16);
    }
    float lse[4];
    #pragma unroll
    for (int r = 0; r < 4; ++r) lse[r] = logf(sum[r]) + mx[r];

    #pragma unroll
    for (int nt = 0; nt < 3; ++nt) {
        int col = nt * 16 + m;
        if (col >= ODIM) continue;
        #pragma unroll
        for (int r = 0; r < 4; ++r) {
            int rowg = base + wave * 16 + q * 4 + r;
            if (rowg >= N_NODES) continue;
            out[(size_t)rowg * ODIM + col] = z[nt][r] - lse[r];
        }
    }
}

// ---------------------------------------------------------------------------
extern "C" void kernel_launch(void* const* d_in, const int* in_sizes, int n_in,
                              void* d_out, int out_size, void* d_ws, size_t ws_size,
                              hipStream_t stream) {
    const float* x   = (const float*)d_in[0];
    const int*   ei  = (const int*)d_in[1];
    const int E = in_sizes[1] / 2;
    const int* src = ei;
    const int* dst = ei + E;

    const float* W1l = (const float*)d_in[2];
    const float* b1  = (const float*)d_in[3];
    const float* W1r = (const float*)d_in[4];
    const float* W2l = (const float*)d_in[5];
    const float* b2  = (const float*)d_in[6];
    const float* W2r = (const float*)d_in[7];
    const float* W3l = (const float*)d_in[8];
    const float* b3  = (const float*)d_in[9];
    const float* W3r = (const float*)d_in[10];
    const float* Wf1 = (const float*)d_in[11];
    const float* bf1 = (const float*)d_in[12];
    const float* Wf2 = (const float*)d_in[13];
    const float* bf2 = (const float*)d_in[14];

    float* out     = (float*)d_out;
    float* outTail = out + (size_t)N_NODES * ODIM;   // tuple part 2: h [N,128] fp32

    // CSR arrays live in d_out HEAD (overwritten by final softmax,
    // which launches after the last CSR use).
    int* ic = (int*)out;            // 100352 ints
    int* pc = ic + 100352;          // 100352 ints
    int* bs = pc + 100352;          // 1024 ints
    int* cs = bs + 1024;            // E ints  (total ~3.4 MB)

    // Workspace (u16 units): X16 | F16a | F16b | A16 | Wpk(7x16384) | Wf2p
    const size_t FEAT16 = (size_t)N_NODES * HDIM;   // 12.8M u16 = 25.6 MB
    u16* X16  = (u16*)d_ws;
    u16* F16a = X16  + FEAT16;
    u16* F16b = F16a + FEAT16;
    u16* A16  = F16b + FEAT16;
    u16* Wpk  = A16  + FEAT16;                      // 7*16384 u16
    u16* Wp_1l = Wpk + 0 * 16384;
    u16* Wp_1r = Wpk + 1 * 16384;
    u16* Wp_2l = Wpk + 2 * 16384;
    u16* Wp_2r = Wpk + 3 * 16384;
    u16* Wp_3l = Wpk + 4 * 16384;
    u16* Wp_3r = Wpk + 5 * 16384;
    u16* Wp_f1 = Wpk + 6 * 16384;
    u16* Wf2p  = Wpk + 7 * 16384;                   // 6144 u16

    const int gemmGrid   = (N_NODES + 127) / 128; // 782
    const int headGrid   = (N_NODES + 63) / 64;   // 1563
    const int gatherGrid = N_NODES / 16;          // 6250 (16 nodes/block, exact)
    const int edgeGrid   = (E + 255) / 256;       // 2500
    const int cvtGrid    = (N_NODES * HDIM / 2 + 255) / 256;  // 25000

    // ---- CSR build ----
    hipMemsetAsync(ic, 0, N_NODES * sizeof(int), stream);
    count_deg_kernel<<<edgeGrid, 256, 0, stream>>>(dst, ic, E);
    block_sum_kernel<<<NBLK, 256, 0, stream>>>(ic, bs, N_NODES);
    scan_bs_kernel<<<1, 512, 0, stream>>>(bs, NBLK);
    scan_block_kernel<<<NBLK, 256, 0, stream>>>(ic, bs, pc, N_NODES);
    fill_kernel<<<edgeGrid, 256, 0, stream>>>(src, dst, pc, cs, E);

    // ---- prep: x -> bf16, pack weights ----
    f2bf_kernel<<<cvtGrid, 256, 0, stream>>>((const float2*)x, (u32*)X16, N_NODES * HDIM / 2);
    WPtrs wp; wp.w[0] = W1l; wp.w[1] = W1r; wp.w[2] = W2l; wp.w[3] = W2r;
    wp.w[4] = W3l; wp.w[5] = W3r; wp.w[6] = Wf1;
    pack_w_kernel<<<dim3(64, 7), 256, 0, stream>>>(wp, Wpk);
    pack_wf2_kernel<<<24, 256, 0, stream>>>(Wf2, Wf2p);

    // ---- layer 1: X16 -> F16a ----
    gather_mean_grp_kernel<<<gatherGrid, 256, 0, stream>>>((const u32*)X16, cs, pc, ic, (u32*)A16);
    mfma_gemm_kernel<<<gemmGrid, 256, 0, stream>>>(A16, X16, Wp_1l, Wp_1r, b1, F16a, nullptr, 1);

    // ---- layer 2: F16a -> F16b ----
    gather_mean_grp_kernel<<<gatherGrid, 256, 0, stream>>>((const u32*)F16a, cs, pc, ic, (u32*)A16);
    mfma_gemm_kernel<<<gemmGrid, 256, 0, stream>>>(A16, F16a, Wp_2l, Wp_2r, b2, F16b, nullptr, 1);

    // ---- layer 3: F16b -> F16a (bf16) + outTail (fp32 h3), no relu ----
    gather_mean_grp_kernel<<<gatherGrid, 256, 0, stream>>>((const u32*)F16b, cs, pc, ic, (u32*)A16);
    mfma_gemm_kernel<<<gemmGrid, 256, 0, stream>>>(A16, F16b, Wp_3l, Wp_3r, b3, F16a, outTail, 0);

    // ---- fused MLP head + log_softmax -> out head (overwrites CSR debris) ----
    mfma_head_kernel<<<headGrid, 256, 0, stream>>>(F16a, Wp_f1, bf1, Wf2p, bf2, out);
}